// Round 1
// baseline (586.449 us; speedup 1.0000x reference)
//
#include <hip/hip_runtime.h>
#include <hip/hip_bf16.h>
#include <math.h>

#define NN 4096      // nodes
#define NE 16384     // edges
#define FIN 64
#define FE 16
#define HIDD 128
#define OUTD 64
#define NG 32
#define EP (NE + NN) // edges + self loops

// ---------- helpers for float atomicMax via ordered-uint encoding ----------
__device__ __forceinline__ unsigned enc_f(float f) {
    unsigned u = __float_as_uint(f);
    return (u & 0x80000000u) ? ~u : (u | 0x80000000u);
}
__device__ __forceinline__ float dec_f(unsigned u) {
    return (u & 0x80000000u) ? __uint_as_float(u ^ 0x80000000u) : __uint_as_float(~u);
}

// ---------- EdgeMLP layers 1+2 fused: edge_attr[E,16] -> h[E,64] ----------
__global__ void k_edge_mlp(const float* __restrict__ ea,
                           const float* __restrict__ w1, const float* __restrict__ b1,
                           const float* __restrict__ w2, const float* __restrict__ b2,
                           float* __restrict__ h_out) {
    __shared__ float h1s[8][HIDD];
    int e0 = blockIdx.x * 8;
    int tid = threadIdx.x; // 128
    for (int e1 = 0; e1 < 8; ++e1) {
        int e = e0 + e1;
        float acc = b1[tid];
#pragma unroll
        for (int i = 0; i < FE; ++i) acc += ea[e * FE + i] * w1[i * HIDD + tid];
        h1s[e1][tid] = fmaxf(acc, 0.f);
    }
    __syncthreads();
    int j = tid & 63;
    int eh = (tid >> 6) * 4; // 0 or 4
    for (int e1 = eh; e1 < eh + 4; ++e1) {
        float acc = b2[j];
#pragma unroll 16
        for (int k = 0; k < HIDD; ++k) acc += h1s[e1][k] * w2[k * 64 + j];
        h_out[(size_t)(e0 + e1) * 64 + j] = fmaxf(acc, 0.f);
    }
}

// ---------- B[n,o] = sum_i x[n,i] * e_b3[i*128+o] ----------
__global__ void k_bias(const float* __restrict__ X, const float* __restrict__ b3,
                       float* __restrict__ Bb) {
    int n = blockIdx.x, o = threadIdx.x;
    float acc = 0.f;
#pragma unroll 16
    for (int i = 0; i < FIN; ++i) acc += X[n * FIN + i] * b3[i * HIDD + o];
    Bb[(size_t)n * HIDD + o] = acc;
}

// ---------- T[nloc, c*128+o] = sum_i X[lo+nloc, i] * w3[c*8192 + i*128 + o] ----------
// GEMM: M=npc, N=8192, K=64. Tile 64x64, block 256, each thread 4x4.
__global__ void k_gemm_T(const float* __restrict__ X, const float* __restrict__ w3,
                         float* __restrict__ T, int node_lo) {
    __shared__ float As[64][65];
    __shared__ float Bs[64][65];
    int bm = blockIdx.x, bn = blockIdx.y;
    int tid = threadIdx.x; // 256
    int row0 = node_lo + bm * 64;
    int c = bn >> 1;
    int o0 = (bn & 1) * 64;
    {
        int m = tid >> 2;
        int kst = (tid & 3) * 16;
        const float* src = &X[(size_t)(row0 + m) * FIN + kst];
#pragma unroll
        for (int t = 0; t < 16; ++t) As[m][kst + t] = src[t];
        int k = tid >> 2;
        int nst = (tid & 3) * 16;
        const float* srcb = &w3[(size_t)c * 8192 + (size_t)k * HIDD + o0 + nst];
#pragma unroll
        for (int t = 0; t < 16; ++t) Bs[k][nst + t] = srcb[t];
    }
    __syncthreads();
    int tx = tid & 15, ty = tid >> 4;
    float acc[4][4];
#pragma unroll
    for (int i = 0; i < 4; ++i)
#pragma unroll
        for (int j = 0; j < 4; ++j) acc[i][j] = 0.f;
#pragma unroll 8
    for (int k = 0; k < 64; ++k) {
        float a[4], b[4];
#pragma unroll
        for (int i = 0; i < 4; ++i) a[i] = As[ty * 4 + i][k];
#pragma unroll
        for (int j = 0; j < 4; ++j) b[j] = Bs[k][tx * 4 + j];
#pragma unroll
        for (int i = 0; i < 4; ++i)
#pragma unroll
            for (int j = 0; j < 4; ++j) acc[i][j] += a[i] * b[j];
    }
#pragma unroll
    for (int i = 0; i < 4; ++i) {
        size_t row = (size_t)(bm * 64 + ty * 4 + i);
        float4 v = make_float4(acc[i][0], acc[i][1], acc[i][2], acc[i][3]);
        *(float4*)&T[row * 8192 + bn * 64 + tx * 4] = v;
    }
}

// ---------- msg[e,o] = B[s,o] + sum_c h[e,c]*T[s-lo,c,o]; atomicAdd into agg[dst] ----------
__global__ void k_msg(const float* __restrict__ T, const float* __restrict__ h,
                      const float* __restrict__ Bb, const int* __restrict__ src,
                      const int* __restrict__ dst, float* __restrict__ agg,
                      int node_lo, int node_hi) {
    int e = blockIdx.x;
    int s = src[e];
    if (s < node_lo || s >= node_hi) return;
    int d = dst[e];
    int o = threadIdx.x; // 128
    const float* Trow = &T[(size_t)(s - node_lo) * 8192 + o];
    const float* he = &h[(size_t)e * 64];
    float acc = Bb[(size_t)s * HIDD + o];
#pragma unroll 16
    for (int c = 0; c < 64; ++c) acc += he[c] * Trow[(size_t)c * HIDD];
    atomicAdd(&agg[(size_t)d * HIDD + o], acc);
}

// ---------- h1 = relu(agg + x@root_w + conv1_b) ----------
__global__ void k_h1(const float* __restrict__ agg, const float* __restrict__ X,
                     const float* __restrict__ rw, const float* __restrict__ cb,
                     float* __restrict__ h1) {
    int n = blockIdx.x, o = threadIdx.x;
    float acc = agg[(size_t)n * HIDD + o] + cb[o];
#pragma unroll 16
    for (int i = 0; i < FIN; ++i) acc += X[n * FIN + i] * rw[i * HIDD + o];
    h1[(size_t)n * HIDD + o] = fmaxf(acc, 0.f);
}

// ---------- hp = h1 @ gat_w ----------
__global__ void k_hp(const float* __restrict__ h1, const float* __restrict__ gw,
                     float* __restrict__ hp) {
    int n = blockIdx.x, o = threadIdx.x;
    float acc = 0.f;
#pragma unroll 16
    for (int k = 0; k < HIDD; ++k) acc += h1[(size_t)n * HIDD + k] * gw[k * HIDD + o];
    hp[(size_t)n * HIDD + o] = acc;
}

// ---------- a_s[n], a_d[n] dot products ----------
__global__ void k_asad(const float* __restrict__ hp, const float* __restrict__ asw,
                       const float* __restrict__ adw, float* __restrict__ a_s,
                       float* __restrict__ a_d) {
    int n = blockIdx.x, o = threadIdx.x; // 128
    float v = hp[(size_t)n * HIDD + o];
    float p1 = v * asw[o], p2 = v * adw[o];
#pragma unroll
    for (int off = 32; off; off >>= 1) {
        p1 += __shfl_down(p1, off);
        p2 += __shfl_down(p2, off);
    }
    __shared__ float s1[2], s2[2];
    if ((o & 63) == 0) { s1[o >> 6] = p1; s2[o >> 6] = p2; }
    __syncthreads();
    if (o == 0) { a_s[n] = s1[0] + s1[1]; a_d[n] = s2[0] + s2[1]; }
}

// ---------- GAT attention: leaky-relu scores + segment max ----------
__global__ void k_evmax(const int* __restrict__ src, const int* __restrict__ dst,
                        const float* __restrict__ a_s, const float* __restrict__ a_d,
                        float* __restrict__ ev, unsigned* __restrict__ mmax) {
    int e = blockIdx.x * blockDim.x + threadIdx.x;
    if (e >= EP) return;
    int si, di;
    if (e < NE) { si = src[e]; di = dst[e]; } else { si = di = e - NE; }
    float x = a_s[si] + a_d[di];
    float v = x > 0.f ? x : 0.2f * x;
    ev[e] = v;
    atomicMax(&mmax[di], enc_f(v));
}

__global__ void k_exden(const int* __restrict__ dst, const float* __restrict__ ev,
                        const unsigned* __restrict__ mmax, float* __restrict__ ex,
                        float* __restrict__ denom) {
    int e = blockIdx.x * blockDim.x + threadIdx.x;
    if (e >= EP) return;
    int di = (e < NE) ? dst[e] : e - NE;
    float m = dec_f(mmax[di]);
    float v = expf(ev[e] - m);
    ex[e] = v;
    atomicAdd(&denom[di], v);
}

__global__ void k_gat_scatter(const int* __restrict__ src, const int* __restrict__ dst,
                              const float* __restrict__ ex, const float* __restrict__ denom,
                              const float* __restrict__ hp, float* __restrict__ h2agg) {
    int e = blockIdx.x;
    int si, di;
    if (e < NE) { si = src[e]; di = dst[e]; } else { si = di = e - NE; }
    float alpha = ex[e] / (denom[di] + 1e-16f);
    int o = threadIdx.x; // 128
    atomicAdd(&h2agg[(size_t)di * HIDD + o], alpha * hp[(size_t)si * HIDD + o]);
}

// ---------- mean-pool accumulate ----------
__global__ void k_pool(const float* __restrict__ h2agg, const float* __restrict__ gb,
                       const int* __restrict__ batch, float* __restrict__ pooled,
                       float* __restrict__ cnt) {
    int n = blockIdx.x, o = threadIdx.x;
    int g = batch[n];
    float v = fmaxf(h2agg[(size_t)n * HIDD + o] + gb[o], 0.f);
    atomicAdd(&pooled[g * HIDD + o], v);
    if (o == 0) atomicAdd(&cnt[g], 1.0f);
}

// ---------- fc1 ----------
__global__ void k_fc1(const float* __restrict__ pooled, const float* __restrict__ cnt,
                      const float* __restrict__ w, const float* __restrict__ b,
                      float* __restrict__ z) {
    int g = blockIdx.x, j = threadIdx.x; // 64
    float c = fmaxf(cnt[g], 1.0f);
    float acc = b[j];
#pragma unroll 16
    for (int o = 0; o < HIDD; ++o) acc += (pooled[g * HIDD + o] / c) * w[o * OUTD + j];
    z[g * OUTD + j] = fmaxf(acc, 0.f);
}

// ---------- final: sigmoid(|z1-z2| @ fc2_w + fc2_b) ----------
__global__ void k_final(const float* __restrict__ z1, const float* __restrict__ z2,
                        const float* __restrict__ w, const float* __restrict__ b,
                        float* __restrict__ out) {
    int g = threadIdx.x; // 32
    float acc = b[0];
#pragma unroll
    for (int j = 0; j < OUTD; ++j) acc += fabsf(z1[g * OUTD + j] - z2[g * OUTD + j]) * w[j];
    out[g] = 1.f / (1.f + expf(-acc));
}

extern "C" void kernel_launch(void* const* d_in, const int* in_sizes, int n_in,
                              void* d_out, int out_size, void* d_ws, size_t ws_size,
                              hipStream_t stream) {
    const float* xg[2]     = {(const float*)d_in[0], (const float*)d_in[4]};
    const int*   eig[2]    = {(const int*)d_in[1], (const int*)d_in[5]};
    const float* eattr[2]  = {(const float*)d_in[2], (const float*)d_in[6]};
    const int*   batchg[2] = {(const int*)d_in[3], (const int*)d_in[7]};
    const float* e_w1 = (const float*)d_in[8];
    const float* e_b1 = (const float*)d_in[9];
    const float* e_w2 = (const float*)d_in[10];
    const float* e_b2 = (const float*)d_in[11];
    const float* e_w3 = (const float*)d_in[12];
    const float* e_b3 = (const float*)d_in[13];
    const float* root_w = (const float*)d_in[14];
    const float* conv1_b = (const float*)d_in[15];
    const float* gat_w = (const float*)d_in[16];
    const float* att_src = (const float*)d_in[17];
    const float* att_dst = (const float*)d_in[18];
    const float* gat_b = (const float*)d_in[19];
    const float* fc1_w = (const float*)d_in[20];
    const float* fc1_b = (const float*)d_in[21];
    const float* fc2_w = (const float*)d_in[22];
    const float* fc2_b = (const float*)d_in[23];

    float* ws = (float*)d_ws;
    size_t off = 0;
    auto alloc = [&](size_t n) { float* p = ws + off; off += n; return p; };
    float* h      = alloc((size_t)NE * 64);
    float* Bb     = alloc((size_t)NN * HIDD);
    float* agg    = alloc((size_t)NN * HIDD);
    float* h1     = alloc((size_t)NN * HIDD);
    float* hp     = alloc((size_t)NN * HIDD);
    float* a_s    = alloc(NN);
    float* a_d    = alloc(NN);
    unsigned* mmax = (unsigned*)alloc(NN);
    float* denom  = alloc(NN);
    float* ev     = alloc(EP);
    float* ex     = alloc(EP);
    float* h2agg  = alloc((size_t)NN * HIDD);
    float* pooled = alloc((size_t)NG * HIDD);
    float* cnt    = alloc(NG);
    float* zz     = alloc((size_t)2 * NG * OUTD);
    float* T      = ws + off;

    size_t t_avail = (ws_size / 4 > off) ? (ws_size / 4 - off) : 0;
    int npc = NN; // nodes per chunk (power of two, >=64)
    while (npc > 64 && (size_t)npc * 8192 > t_avail) npc >>= 1;
    int nchunk = NN / npc;

    for (int gi = 0; gi < 2; ++gi) {
        const int* srcp = eig[gi];
        const int* dstp = eig[gi] + NE;
        hipMemsetAsync(agg, 0, (size_t)NN * HIDD * 4, stream);
        hipMemsetAsync(mmax, 0, (size_t)NN * 4, stream);
        hipMemsetAsync(denom, 0, (size_t)NN * 4, stream);
        hipMemsetAsync(h2agg, 0, (size_t)NN * HIDD * 4, stream);
        hipMemsetAsync(pooled, 0, (size_t)NG * HIDD * 4, stream);
        hipMemsetAsync(cnt, 0, (size_t)NG * 4, stream);

        k_edge_mlp<<<NE / 8, 128, 0, stream>>>(eattr[gi], e_w1, e_b1, e_w2, e_b2, h);
        k_bias<<<NN, HIDD, 0, stream>>>(xg[gi], e_b3, Bb);
        for (int c = 0; c < nchunk; ++c) {
            int lo = c * npc;
            k_gemm_T<<<dim3(npc / 64, 128), 256, 0, stream>>>(xg[gi], e_w3, T, lo);
            k_msg<<<NE, HIDD, 0, stream>>>(T, h, Bb, srcp, dstp, agg, lo, lo + npc);
        }
        k_h1<<<NN, HIDD, 0, stream>>>(agg, xg[gi], root_w, conv1_b, h1);
        k_hp<<<NN, HIDD, 0, stream>>>(h1, gat_w, hp);
        k_asad<<<NN, HIDD, 0, stream>>>(hp, att_src, att_dst, a_s, a_d);
        k_evmax<<<(EP + 255) / 256, 256, 0, stream>>>(srcp, dstp, a_s, a_d, ev, mmax);
        k_exden<<<(EP + 255) / 256, 256, 0, stream>>>(dstp, ev, mmax, ex, denom);
        k_gat_scatter<<<EP, HIDD, 0, stream>>>(srcp, dstp, ex, denom, hp, h2agg);
        k_pool<<<NN, HIDD, 0, stream>>>(h2agg, gat_b, batchg[gi], pooled, cnt);
        k_fc1<<<NG, OUTD, 0, stream>>>(pooled, cnt, fc1_w, fc1_b, zz + (size_t)gi * NG * OUTD);
    }
    k_final<<<1, NG, 0, stream>>>(zz, zz + (size_t)NG * OUTD, fc2_w, fc2_b, (float*)d_out);
}

// Round 2
// 428.179 us; speedup vs baseline: 1.3696x; 1.3696x over previous
//
#include <hip/hip_runtime.h>
#include <hip/hip_bf16.h>
#include <math.h>

#define NN 4096      // nodes
#define NE 16384     // edges
#define FIN 64
#define FE 16
#define HIDD 128
#define OUTD 64
#define NG 32
#define EP (NE + NN) // edges + self loops
#define KSPLIT 4

typedef __attribute__((ext_vector_type(8))) short s8v;
typedef __attribute__((ext_vector_type(4))) unsigned u4v;
typedef __attribute__((ext_vector_type(4))) float f4v;

union FragU { u4v u; s8v s; };

// ---------- helpers for float atomicMax via ordered-uint encoding ----------
__device__ __forceinline__ unsigned enc_f(float f) {
    unsigned u = __float_as_uint(f);
    return (u & 0x80000000u) ? ~u : (u | 0x80000000u);
}
__device__ __forceinline__ float dec_f(unsigned u) {
    return (u & 0x80000000u) ? __uint_as_float(u ^ 0x80000000u) : __uint_as_float(~u);
}

__device__ __forceinline__ unsigned bf16_rne(float v) {
    unsigned b = __float_as_uint(v);
    return (b + 0x7FFFu + ((b >> 16) & 1u)) >> 16;
}

__device__ __forceinline__ void glds16(const void* g, void* l) {
    __builtin_amdgcn_global_load_lds(
        (const __attribute__((address_space(1))) unsigned*)g,
        (__attribute__((address_space(3))) unsigned*)l, 16, 0, 0);
}

// ---------- EdgeMLP: edge_attr[E,16] -> hT[64 c][NE] (transposed output) ----------
__global__ void k_edge_mlp(const float* __restrict__ ea,
                           const float* __restrict__ w1, const float* __restrict__ b1,
                           const float* __restrict__ w2, const float* __restrict__ b2,
                           float* __restrict__ hT) {
    __shared__ float h1s[8][HIDD];
    __shared__ float h2s[8][64];
    int e0 = blockIdx.x * 8;
    int tid = threadIdx.x; // 128
    for (int e1 = 0; e1 < 8; ++e1) {
        int e = e0 + e1;
        float acc = b1[tid];
#pragma unroll
        for (int i = 0; i < FE; ++i) acc += ea[e * FE + i] * w1[i * HIDD + tid];
        h1s[e1][tid] = fmaxf(acc, 0.f);
    }
    __syncthreads();
    int j = tid & 63;
    int eh = (tid >> 6) * 4; // 0 or 4
    for (int e1 = eh; e1 < eh + 4; ++e1) {
        float acc = b2[j];
#pragma unroll 16
        for (int k = 0; k < HIDD; ++k) acc += h1s[e1][k] * w2[k * 64 + j];
        h2s[e1][j] = fmaxf(acc, 0.f);
    }
    __syncthreads();
    // transposed write: thread (j2, q) writes hT[j2][e0 + q*4 .. +3]
    int j2 = tid & 63, q = tid >> 6;
    float4 v;
    v.x = h2s[q * 4 + 0][j2];
    v.y = h2s[q * 4 + 1][j2];
    v.z = h2s[q * 4 + 2][j2];
    v.w = h2s[q * 4 + 3][j2];
    *(float4*)&hT[(size_t)j2 * NE + e0 + q * 4] = v;
}

// ---------- split e_w3 into bf16 hi/lo images in LDS-image (swizzled) layout ----------
// B[k = c*64+i][o] = e_w3[c*8192 + i*128 + o]; image u16 idx = c*8192 + ((o*64+i) ^ ((o&7)<<3))
__global__ void k_splitB(const float* __restrict__ w3,
                         unsigned short* __restrict__ B1g, unsigned short* __restrict__ B2g) {
    int g = blockIdx.x * 256 + threadIdx.x; // 524288 total
    int o = g & 127, i = (g >> 7) & 63, c = g >> 13;
    float v = w3[(size_t)c * 8192 + i * 128 + o];
    unsigned r1 = bf16_rne(v);
    float res = v - __uint_as_float(r1 << 16);
    unsigned r2 = bf16_rne(res);
    unsigned idx = ((unsigned)c << 13) + (((o << 6) + i) ^ ((o & 7) << 3));
    B1g[idx] = (unsigned short)r1;
    B2g[idx] = (unsigned short)r2;
}

// ---------- Bb[n,o] = sum_i x[n,i] * e_b3[i*128+o] ----------
__global__ void k_bias(const float* __restrict__ X, const float* __restrict__ b3,
                       float* __restrict__ Bb) {
    int n = blockIdx.x, o = threadIdx.x;
    float acc = 0.f;
#pragma unroll 16
    for (int i = 0; i < FIN; ++i) acc += X[n * FIN + i] * b3[i * HIDD + o];
    Bb[(size_t)n * HIDD + o] = acc;
}

// ---------- fused NNConv message GEMM: agg[dst] += (h(e) x xs(e)) @ W3 + Bb[src] ----------
// M=16384 edges (128/block), N=128, K=4096 (KSPLIT z-blocks x 16 chunks of 64)
__global__ void __launch_bounds__(256, 2)
k_nnconv(const float* __restrict__ x, const float* __restrict__ hT,
         const unsigned short* __restrict__ B1g, const unsigned short* __restrict__ B2g,
         const float* __restrict__ Bb, const int* __restrict__ src,
         const int* __restrict__ dst, float* __restrict__ agg) {
    __shared__ __align__(16) char smem[65536];
    char* B1s = smem;            // 16 KB  [128 o][64 k] bf16, swizzled
    char* B2s = smem + 16384;    // 16 KB
    char* A1s = smem + 32768;    // 16 KB  [128 e][64 i] bf16, swizzled
    char* A2s = smem + 49152;    // 16 KB

    int t = threadIdx.x;          // 256
    int bm = blockIdx.x;          // 0..127
    int z = blockIdx.y;           // 0..KSPLIT-1
    int e0 = bm * 128;
    int wave = t >> 6, l = t & 63;
    int wm = wave >> 1, wn = wave & 1;
    int q4 = l >> 4, c16 = l & 15;

    // prologue: per-thread xs slice in registers (chunk-invariant)
    int eloc_t = t >> 1;
    int i0 = (t & 1) * 32;
    int eg_t = e0 + eloc_t;
    int s_t = src[eg_t];
    float xs[32];
    {
        const float4* xr = (const float4*)&x[(size_t)s_t * FIN + i0];
#pragma unroll
        for (int q = 0; q < 8; ++q) ((float4*)xs)[q] = xr[q];
    }

    f4v acc[4][4];
#pragma unroll
    for (int a = 0; a < 4; ++a)
#pragma unroll
        for (int b = 0; b < 4; ++b) acc[a][b] = (f4v){0.f, 0.f, 0.f, 0.f};

    for (int cl = 0; cl < 64 / KSPLIT; ++cl) {
        int cg = z * (64 / KSPLIT) + cl;
        __syncthreads(); // prior chunk's LDS reads complete (WAR)

        // stage B1,B2 chunk: linear copy of pre-swizzled image (16 KB each)
        const char* b1src = (const char*)B1g + (size_t)cg * 16384;
        const char* b2src = (const char*)B2g + (size_t)cg * 16384;
        int woff = wave << 10;
#pragma unroll
        for (int k2 = 0; k2 < 4; ++k2) {
            glds16(b1src + k2 * 4096 + t * 16, B1s + k2 * 4096 + woff);
            glds16(b2src + k2 * 4096 + t * 16, B2s + k2 * 4096 + woff);
        }

        // synthesize A1,A2 for this chunk: A[e][i] = h[e][cg] * xs[e][i]
        float hv = hT[(size_t)cg * NE + eg_t];
#pragma unroll
        for (int q = 0; q < 4; ++q) {
            u4v w1, w2;
#pragma unroll
            for (int p = 0; p < 4; ++p) {
                float p0 = hv * xs[q * 8 + p * 2];
                float p1 = hv * xs[q * 8 + p * 2 + 1];
                unsigned b0 = __float_as_uint(p0), b1 = __float_as_uint(p1);
                unsigned a1 = (b0 >> 16) | (b1 & 0xFFFF0000u);
                float r0 = p0 - __uint_as_float(b0 & 0xFFFF0000u);
                float r1 = p1 - __uint_as_float(b1 & 0xFFFF0000u);
                unsigned a2 = (__float_as_uint(r0) >> 16) | (__float_as_uint(r1) & 0xFFFF0000u);
                w1[p] = a1; w2[p] = a2;
            }
            int byte = eloc_t * 128 + (((i0 + q * 8) * 2) ^ ((eloc_t & 7) << 4));
            *(u4v*)(A1s + byte) = w1;
            *(u4v*)(A2s + byte) = w2;
        }
        __syncthreads(); // B staged (vmcnt) + A written (lgkmcnt)

#pragma unroll
        for (int kf = 0; kf < 2; ++kf) {
            // B fragments for this wave's 64-col half, both matrices
            FragU bf1[4], bf2[4];
#pragma unroll
            for (int nf = 0; nf < 4; ++nf) {
                int o = wn * 64 + nf * 16 + c16;
                int byte = o * 128 + ((kf * 64 + q4 * 16) ^ ((o & 7) << 4));
                bf1[nf].u = *(const u4v*)(B1s + byte);
                bf2[nf].u = *(const u4v*)(B2s + byte);
            }
#pragma unroll
            for (int mf = 0; mf < 4; ++mf) {
                int e = wm * 64 + mf * 16 + c16;
                int byte = e * 128 + ((kf * 64 + q4 * 16) ^ ((e & 7) << 4));
                FragU a1, a2;
                a1.u = *(const u4v*)(A1s + byte);
                a2.u = *(const u4v*)(A2s + byte);
#pragma unroll
                for (int nf = 0; nf < 4; ++nf) {
                    acc[mf][nf] = __builtin_amdgcn_mfma_f32_16x16x32_bf16(a1.s, bf1[nf].s, acc[mf][nf], 0, 0, 0);
                    acc[mf][nf] = __builtin_amdgcn_mfma_f32_16x16x32_bf16(a1.s, bf2[nf].s, acc[mf][nf], 0, 0, 0);
                    acc[mf][nf] = __builtin_amdgcn_mfma_f32_16x16x32_bf16(a2.s, bf1[nf].s, acc[mf][nf], 0, 0, 0);
                }
            }
        }
    }

    // epilogue: scatter-add to agg[dst]; add Bb[src] once (z==0)
#pragma unroll
    for (int mf = 0; mf < 4; ++mf) {
#pragma unroll
        for (int r = 0; r < 4; ++r) {
            int eloc = wm * 64 + mf * 16 + q4 * 4 + r;
            int eg = e0 + eloc;
            int s_ = src[eg], d_ = dst[eg];
#pragma unroll
            for (int nf = 0; nf < 4; ++nf) {
                int o = wn * 64 + nf * 16 + c16;
                float v = acc[mf][nf][r];
                if (z == 0) v += Bb[(size_t)s_ * HIDD + o];
                atomicAdd(&agg[(size_t)d_ * HIDD + o], v);
            }
        }
    }
}

// ---------- h1 = relu(agg + x@root_w + conv1_b) ----------
__global__ void k_h1(const float* __restrict__ agg, const float* __restrict__ X,
                     const float* __restrict__ rw, const float* __restrict__ cb,
                     float* __restrict__ h1) {
    int n = blockIdx.x, o = threadIdx.x;
    float acc = agg[(size_t)n * HIDD + o] + cb[o];
#pragma unroll 16
    for (int i = 0; i < FIN; ++i) acc += X[n * FIN + i] * rw[i * HIDD + o];
    h1[(size_t)n * HIDD + o] = fmaxf(acc, 0.f);
}

// ---------- hp = h1 @ gat_w ----------
__global__ void k_hp(const float* __restrict__ h1, const float* __restrict__ gw,
                     float* __restrict__ hp) {
    int n = blockIdx.x, o = threadIdx.x;
    float acc = 0.f;
#pragma unroll 16
    for (int k = 0; k < HIDD; ++k) acc += h1[(size_t)n * HIDD + k] * gw[k * HIDD + o];
    hp[(size_t)n * HIDD + o] = acc;
}

// ---------- a_s[n], a_d[n] dot products ----------
__global__ void k_asad(const float* __restrict__ hp, const float* __restrict__ asw,
                       const float* __restrict__ adw, float* __restrict__ a_s,
                       float* __restrict__ a_d) {
    int n = blockIdx.x, o = threadIdx.x; // 128
    float v = hp[(size_t)n * HIDD + o];
    float p1 = v * asw[o], p2 = v * adw[o];
#pragma unroll
    for (int off = 32; off; off >>= 1) {
        p1 += __shfl_down(p1, off);
        p2 += __shfl_down(p2, off);
    }
    __shared__ float s1[2], s2[2];
    if ((o & 63) == 0) { s1[o >> 6] = p1; s2[o >> 6] = p2; }
    __syncthreads();
    if (o == 0) { a_s[n] = s1[0] + s1[1]; a_d[n] = s2[0] + s2[1]; }
}

// ---------- GAT attention: leaky-relu scores + segment max ----------
__global__ void k_evmax(const int* __restrict__ src, const int* __restrict__ dst,
                        const float* __restrict__ a_s, const float* __restrict__ a_d,
                        float* __restrict__ ev, unsigned* __restrict__ mmax) {
    int e = blockIdx.x * blockDim.x + threadIdx.x;
    if (e >= EP) return;
    int si, di;
    if (e < NE) { si = src[e]; di = dst[e]; } else { si = di = e - NE; }
    float x = a_s[si] + a_d[di];
    float v = x > 0.f ? x : 0.2f * x;
    ev[e] = v;
    atomicMax(&mmax[di], enc_f(v));
}

__global__ void k_exden(const int* __restrict__ dst, const float* __restrict__ ev,
                        const unsigned* __restrict__ mmax, float* __restrict__ ex,
                        float* __restrict__ denom) {
    int e = blockIdx.x * blockDim.x + threadIdx.x;
    if (e >= EP) return;
    int di = (e < NE) ? dst[e] : e - NE;
    float m = dec_f(mmax[di]);
    float v = expf(ev[e] - m);
    ex[e] = v;
    atomicAdd(&denom[di], v);
}

__global__ void k_gat_scatter(const int* __restrict__ src, const int* __restrict__ dst,
                              const float* __restrict__ ex, const float* __restrict__ denom,
                              const float* __restrict__ hp, float* __restrict__ h2agg) {
    int e = blockIdx.x;
    int si, di;
    if (e < NE) { si = src[e]; di = dst[e]; } else { si = di = e - NE; }
    float alpha = ex[e] / (denom[di] + 1e-16f);
    int o = threadIdx.x; // 128
    atomicAdd(&h2agg[(size_t)di * HIDD + o], alpha * hp[(size_t)si * HIDD + o]);
}

// ---------- mean-pool accumulate ----------
__global__ void k_pool(const float* __restrict__ h2agg, const float* __restrict__ gb,
                       const int* __restrict__ batch, float* __restrict__ pooled,
                       float* __restrict__ cnt) {
    int n = blockIdx.x, o = threadIdx.x;
    int g = batch[n];
    float v = fmaxf(h2agg[(size_t)n * HIDD + o] + gb[o], 0.f);
    atomicAdd(&pooled[g * HIDD + o], v);
    if (o == 0) atomicAdd(&cnt[g], 1.0f);
}

// ---------- fc1 ----------
__global__ void k_fc1(const float* __restrict__ pooled, const float* __restrict__ cnt,
                      const float* __restrict__ w, const float* __restrict__ b,
                      float* __restrict__ z) {
    int g = blockIdx.x, j = threadIdx.x; // 64
    float c = fmaxf(cnt[g], 1.0f);
    float acc = b[j];
#pragma unroll 16
    for (int o = 0; o < HIDD; ++o) acc += (pooled[g * HIDD + o] / c) * w[o * OUTD + j];
    z[g * OUTD + j] = fmaxf(acc, 0.f);
}

// ---------- final: sigmoid(|z1-z2| @ fc2_w + fc2_b) ----------
__global__ void k_final(const float* __restrict__ z1, const float* __restrict__ z2,
                        const float* __restrict__ w, const float* __restrict__ b,
                        float* __restrict__ out) {
    int g = threadIdx.x; // 32
    float acc = b[0];
#pragma unroll
    for (int j = 0; j < OUTD; ++j) acc += fabsf(z1[g * OUTD + j] - z2[g * OUTD + j]) * w[j];
    out[g] = 1.f / (1.f + expf(-acc));
}

extern "C" void kernel_launch(void* const* d_in, const int* in_sizes, int n_in,
                              void* d_out, int out_size, void* d_ws, size_t ws_size,
                              hipStream_t stream) {
    const float* xg[2]     = {(const float*)d_in[0], (const float*)d_in[4]};
    const int*   eig[2]    = {(const int*)d_in[1], (const int*)d_in[5]};
    const float* eattr[2]  = {(const float*)d_in[2], (const float*)d_in[6]};
    const int*   batchg[2] = {(const int*)d_in[3], (const int*)d_in[7]};
    const float* e_w1 = (const float*)d_in[8];
    const float* e_b1 = (const float*)d_in[9];
    const float* e_w2 = (const float*)d_in[10];
    const float* e_b2 = (const float*)d_in[11];
    const float* e_w3 = (const float*)d_in[12];
    const float* e_b3 = (const float*)d_in[13];
    const float* root_w = (const float*)d_in[14];
    const float* conv1_b = (const float*)d_in[15];
    const float* gat_w = (const float*)d_in[16];
    const float* att_src = (const float*)d_in[17];
    const float* att_dst = (const float*)d_in[18];
    const float* gat_b = (const float*)d_in[19];
    const float* fc1_w = (const float*)d_in[20];
    const float* fc1_b = (const float*)d_in[21];
    const float* fc2_w = (const float*)d_in[22];
    const float* fc2_b = (const float*)d_in[23];

    float* ws = (float*)d_ws;
    size_t off = 0;
    auto alloc = [&](size_t n) { float* p = ws + off; off += n; return p; };
    float* hT     = alloc((size_t)64 * NE);          // 4 MB: h transposed [c][e]
    unsigned short* B1g = (unsigned short*)alloc((size_t)4096 * 128 / 2); // 1 MB
    unsigned short* B2g = (unsigned short*)alloc((size_t)4096 * 128 / 2); // 1 MB
    float* Bb     = alloc((size_t)NN * HIDD);
    float* agg    = alloc((size_t)NN * HIDD);
    float* h1     = alloc((size_t)NN * HIDD);
    float* hp     = alloc((size_t)NN * HIDD);
    float* a_s    = alloc(NN);
    float* a_d    = alloc(NN);
    unsigned* mmax = (unsigned*)alloc(NN);
    float* denom  = alloc(NN);
    float* ev     = alloc(EP);
    float* ex     = alloc(EP);
    float* h2agg  = alloc((size_t)NN * HIDD);
    float* pooled = alloc((size_t)NG * HIDD);
    float* cnt    = alloc(NG);
    float* zz     = alloc((size_t)2 * NG * OUTD);

    // graph-independent: split e_w3 into swizzled bf16 hi/lo images (once)
    k_splitB<<<2048, 256, 0, stream>>>(e_w3, B1g, B2g);

    for (int gi = 0; gi < 2; ++gi) {
        const int* srcp = eig[gi];
        const int* dstp = eig[gi] + NE;
        hipMemsetAsync(agg, 0, (size_t)NN * HIDD * 4, stream);
        hipMemsetAsync(mmax, 0, (size_t)NN * 4, stream);
        hipMemsetAsync(denom, 0, (size_t)NN * 4, stream);
        hipMemsetAsync(h2agg, 0, (size_t)NN * HIDD * 4, stream);
        hipMemsetAsync(pooled, 0, (size_t)NG * HIDD * 4, stream);
        hipMemsetAsync(cnt, 0, (size_t)NG * 4, stream);

        k_edge_mlp<<<NE / 8, 128, 0, stream>>>(eattr[gi], e_w1, e_b1, e_w2, e_b2, hT);
        k_bias<<<NN, HIDD, 0, stream>>>(xg[gi], e_b3, Bb);
        k_nnconv<<<dim3(NE / 128, KSPLIT), 256, 0, stream>>>(xg[gi], hT, B1g, B2g, Bb,
                                                             srcp, dstp, agg);
        k_h1<<<NN, HIDD, 0, stream>>>(agg, xg[gi], root_w, conv1_b, h1);
        k_hp<<<NN, HIDD, 0, stream>>>(h1, gat_w, hp);
        k_asad<<<NN, HIDD, 0, stream>>>(hp, att_src, att_dst, a_s, a_d);
        k_evmax<<<(EP + 255) / 256, 256, 0, stream>>>(srcp, dstp, a_s, a_d, ev, mmax);
        k_exden<<<(EP + 255) / 256, 256, 0, stream>>>(dstp, ev, mmax, ex, denom);
        k_gat_scatter<<<EP, HIDD, 0, stream>>>(srcp, dstp, ex, denom, hp, h2agg);
        k_pool<<<NN, HIDD, 0, stream>>>(h2agg, gat_b, batchg[gi], pooled, cnt);
        k_fc1<<<NG, OUTD, 0, stream>>>(pooled, cnt, fc1_w, fc1_b, zz + (size_t)gi * NG * OUTD);
    }
    k_final<<<1, NG, 0, stream>>>(zz, zz + (size_t)NG * OUTD, fc2_w, fc2_b, (float*)d_out);
}

// Round 3
// 308.166 us; speedup vs baseline: 1.9030x; 1.3894x over previous
//
#include <hip/hip_runtime.h>
#include <hip/hip_bf16.h>
#include <math.h>

#define NN 4096      // nodes
#define NE 16384     // edges
#define FIN 64
#define FE 16
#define HIDD 128
#define OUTD 64
#define NG 32
#define EP (NE + NN) // edges + self loops
#define KSPLIT 4
#define NCH (64 / KSPLIT)  // 16 chunks per block

typedef __attribute__((ext_vector_type(8))) short s8v;
typedef __attribute__((ext_vector_type(4))) unsigned u4v;
typedef __attribute__((ext_vector_type(4))) float f4v;

union FragU { u4v u; s8v s; };

__device__ __forceinline__ unsigned enc_f(float f) {
    unsigned u = __float_as_uint(f);
    return (u & 0x80000000u) ? ~u : (u | 0x80000000u);
}
__device__ __forceinline__ float dec_f(unsigned u) {
    return (u & 0x80000000u) ? __uint_as_float(u ^ 0x80000000u) : __uint_as_float(~u);
}

__device__ __forceinline__ unsigned bf16_rne(float v) {
    unsigned b = __float_as_uint(v);
    return (b + 0x7FFFu + ((b >> 16) & 1u)) >> 16;
}

__device__ __forceinline__ void glds16(const void* g, void* l) {
    __builtin_amdgcn_global_load_lds(
        (const __attribute__((address_space(1))) unsigned*)g,
        (__attribute__((address_space(3))) unsigned*)l, 16, 0, 0);
}

// ---------- EdgeMLP: edge_attr[E,16] -> h[E,64] row-major, both graphs ----------
__global__ void k_edge_mlp(const float* __restrict__ ea0, const float* __restrict__ ea1,
                           const float* __restrict__ w1, const float* __restrict__ b1,
                           const float* __restrict__ w2, const float* __restrict__ b2,
                           float* __restrict__ h_0, float* __restrict__ h_1) {
    int gi = blockIdx.y;
    const float* ea = gi ? ea1 : ea0;
    float* h_out = gi ? h_1 : h_0;
    __shared__ float h1s[8][HIDD];
    int e0 = blockIdx.x * 8;
    int tid = threadIdx.x; // 128
    for (int e1 = 0; e1 < 8; ++e1) {
        int e = e0 + e1;
        float acc = b1[tid];
#pragma unroll
        for (int i = 0; i < FE; ++i) acc += ea[e * FE + i] * w1[i * HIDD + tid];
        h1s[e1][tid] = fmaxf(acc, 0.f);
    }
    __syncthreads();
    int j = tid & 63;
    int eh = (tid >> 6) * 4; // 0 or 4
    for (int e1 = eh; e1 < eh + 4; ++e1) {
        float acc = b2[j];
#pragma unroll 16
        for (int k = 0; k < HIDD; ++k) acc += h1s[e1][k] * w2[k * 64 + j];
        h_out[(size_t)(e0 + e1) * 64 + j] = fmaxf(acc, 0.f);
    }
}

// ---------- split e_w3 into bf16 hi/lo images in swizzled LDS-image layout ----------
__global__ void k_splitB(const float* __restrict__ w3,
                         unsigned short* __restrict__ B1g, unsigned short* __restrict__ B2g) {
    int g = blockIdx.x * 256 + threadIdx.x; // 524288 total
    int o = g & 127, i = (g >> 7) & 63, c = g >> 13;
    float v = w3[(size_t)c * 8192 + i * 128 + o];
    unsigned hi = __float_as_uint(v) & 0xFFFF0000u;      // truncated high part
    float res = v - __uint_as_float(hi);
    unsigned r2 = bf16_rne(res);
    unsigned idx = ((unsigned)c << 13) + (((o << 6) + i) ^ ((o & 7) << 3));
    B1g[idx] = (unsigned short)(hi >> 16);
    B2g[idx] = (unsigned short)r2;
}

// ---------- Bb[n,o] = sum_i x[n,i] * e_b3[i*128+o], both graphs ----------
__global__ void k_bias(const float* __restrict__ X0, const float* __restrict__ X1,
                       const float* __restrict__ b3,
                       float* __restrict__ Bb0, float* __restrict__ Bb1) {
    int gi = blockIdx.y;
    const float* X = gi ? X1 : X0;
    float* Bb = gi ? Bb1 : Bb0;
    int n = blockIdx.x, o = threadIdx.x;
    float acc = 0.f;
#pragma unroll 16
    for (int i = 0; i < FIN; ++i) acc += X[n * FIN + i] * b3[i * HIDD + o];
    Bb[(size_t)n * HIDD + o] = acc;
}

// ---------- fused NNConv message GEMM (A in regs, B double-buffered LDS) ----------
// M=16384 edges (128/block), N=128, K=4096 (KSPLIT z x 16 chunks of 64)
// wave tile: 32 rows x 128 cols (mf=2, nf=8)
__global__ void __launch_bounds__(256, 2)
k_nnconv(const float* __restrict__ x0, const float* __restrict__ x1,
         const float* __restrict__ h_0, const float* __restrict__ h_1,
         const unsigned short* __restrict__ B1g, const unsigned short* __restrict__ B2g,
         const float* __restrict__ Bb0, const float* __restrict__ Bb1,
         const int* __restrict__ ei0, const int* __restrict__ ei1,
         float* __restrict__ agg0, float* __restrict__ agg1) {
    __shared__ __align__(16) char smem[65536]; // 2 bufs x (B1 16K | B2 16K)
    int gi = blockIdx.z;
    const float* x = gi ? x1 : x0;
    const float* hh = gi ? h_1 : h_0;
    const float* Bb = gi ? Bb1 : Bb0;
    const int* src = gi ? ei1 : ei0;
    const int* dst = src + NE;
    float* agg = gi ? agg1 : agg0;

    int t = threadIdx.x;          // 256
    int e0 = blockIdx.x * 128;
    int z = blockIdx.y;
    int wv = t >> 6, l = t & 63;
    int q4 = l >> 4, c16 = l & 15;

    // prologue: x slices + h slices for this wave's 2 row-tiles, in registers
    float xs[2][16];  // [mf][kf*8+e]: x[src[row]][kf*32 + q4*8 + e]
    float hs[2][16];  // [mf][cl]:     h[row][z*16 + cl]
#pragma unroll
    for (int mf = 0; mf < 2; ++mf) {
        int r = wv * 32 + mf * 16 + c16;
        int s_ = src[e0 + r];
        const float* xr = &x[(size_t)s_ * FIN];
        *(float4*)&xs[mf][0]  = *(const float4*)&xr[q4 * 8];
        *(float4*)&xs[mf][4]  = *(const float4*)&xr[q4 * 8 + 4];
        *(float4*)&xs[mf][8]  = *(const float4*)&xr[32 + q4 * 8];
        *(float4*)&xs[mf][12] = *(const float4*)&xr[32 + q4 * 8 + 4];
        const float* hr = &hh[(size_t)(e0 + r) * 64 + z * NCH];
        *(float4*)&hs[mf][0]  = *(const float4*)&hr[0];
        *(float4*)&hs[mf][4]  = *(const float4*)&hr[4];
        *(float4*)&hs[mf][8]  = *(const float4*)&hr[8];
        *(float4*)&hs[mf][12] = *(const float4*)&hr[12];
    }

    f4v acc[2][8];
#pragma unroll
    for (int a = 0; a < 2; ++a)
#pragma unroll
        for (int b = 0; b < 8; ++b) acc[a][b] = (f4v){0.f, 0.f, 0.f, 0.f};

    int woff = wv << 10;
#define STAGE(cg, buf)                                                         \
    {                                                                          \
        const char* b1src = (const char*)B1g + (size_t)(cg) * 16384;           \
        const char* b2src = (const char*)B2g + (size_t)(cg) * 16384;           \
        char* B1s_ = smem + (buf) * 32768;                                     \
        char* B2s_ = B1s_ + 16384;                                             \
        _Pragma("unroll")                                                      \
        for (int k2 = 0; k2 < 4; ++k2) {                                       \
            glds16(b1src + k2 * 4096 + t * 16, B1s_ + k2 * 4096 + woff);       \
            glds16(b2src + k2 * 4096 + t * 16, B2s_ + k2 * 4096 + woff);       \
        }                                                                      \
    }

    STAGE(z * NCH, 0);

#pragma unroll 1
    for (int cl = 0; cl < NCH; ++cl) {
        int buf = cl & 1;
        __builtin_amdgcn_s_barrier();          // WAR: all waves done reading buf^1
        __builtin_amdgcn_sched_barrier(0);
        if (cl + 1 < NCH) STAGE(z * NCH + cl + 1, buf ^ 1);

        // synthesize A fragments in registers (overlaps the staging loads)
        FragU a1[2][2], a2[2][2]; // [mf][kf]
#pragma unroll
        for (int mf = 0; mf < 2; ++mf) {
            float hv = hs[mf][cl];
#pragma unroll
            for (int kf = 0; kf < 2; ++kf) {
                u4v w1v, w2v;
#pragma unroll
                for (int p = 0; p < 4; ++p) {
                    float p0 = hv * xs[mf][kf * 8 + 2 * p];
                    float p1 = hv * xs[mf][kf * 8 + 2 * p + 1];
                    unsigned b0 = __float_as_uint(p0), b1 = __float_as_uint(p1);
                    unsigned hi0 = b0 & 0xFFFF0000u, hi1 = b1 & 0xFFFF0000u;
                    w1v[p] = (hi0 >> 16) | hi1;
                    float r0 = p0 - __uint_as_float(hi0);
                    float r1 = p1 - __uint_as_float(hi1);
                    w2v[p] = bf16_rne(r0) | (bf16_rne(r1) << 16);
                }
                a1[mf][kf].u = w1v; a2[mf][kf].u = w2v;
            }
        }

        if (cl + 1 < NCH) { asm volatile("s_waitcnt vmcnt(8)" ::: "memory"); }
        else             { asm volatile("s_waitcnt vmcnt(0)" ::: "memory"); }
        __builtin_amdgcn_sched_barrier(0);
        __builtin_amdgcn_s_barrier();          // buf fully staged for all waves
        __builtin_amdgcn_sched_barrier(0);

        const char* B1s = smem + buf * 32768;
        const char* B2s = B1s + 16384;
#pragma unroll
        for (int kf = 0; kf < 2; ++kf) {
#pragma unroll
            for (int nf = 0; nf < 8; ++nf) {
                int o = nf * 16 + c16;
                int byte = o * 128 + ((kf * 64 + q4 * 16) ^ ((o & 7) << 4));
                FragU bf1, bf2;
                bf1.u = *(const u4v*)(B1s + byte);
                bf2.u = *(const u4v*)(B2s + byte);
#pragma unroll
                for (int mf = 0; mf < 2; ++mf) {
                    acc[mf][nf] = __builtin_amdgcn_mfma_f32_16x16x32_bf16(a1[mf][kf].s, bf1.s, acc[mf][nf], 0, 0, 0);
                    acc[mf][nf] = __builtin_amdgcn_mfma_f32_16x16x32_bf16(a1[mf][kf].s, bf2.s, acc[mf][nf], 0, 0, 0);
                    acc[mf][nf] = __builtin_amdgcn_mfma_f32_16x16x32_bf16(a2[mf][kf].s, bf1.s, acc[mf][nf], 0, 0, 0);
                }
            }
        }
    }
#undef STAGE

    // epilogue: scatter-add to agg[dst]; add Bb[src] once (z==0)
    int z0 = (z == 0);
#pragma unroll
    for (int mf = 0; mf < 2; ++mf) {
#pragma unroll
        for (int j = 0; j < 4; ++j) {
            int r = wv * 32 + mf * 16 + q4 * 4 + j;
            int eg = e0 + r;
            int s_ = src[eg], d_ = dst[eg];
            const float* bbr = &Bb[(size_t)s_ * HIDD];
            float* ar = &agg[(size_t)d_ * HIDD];
#pragma unroll
            for (int nf = 0; nf < 8; ++nf) {
                int o = nf * 16 + c16;
                float v = acc[mf][nf][j];
                if (z0) v += bbr[o];
                atomicAdd(&ar[o], v);
            }
        }
    }
}

// ---------- fused h1 = relu(agg + x@root_w + cb); hp = h1@gat_w; a_s,a_d ----------
__global__ void k_h1hp(const float* __restrict__ agg0, const float* __restrict__ agg1,
                       const float* __restrict__ X0, const float* __restrict__ X1,
                       const float* __restrict__ rw, const float* __restrict__ cb,
                       const float* __restrict__ gw,
                       const float* __restrict__ asw, const float* __restrict__ adw,
                       float* __restrict__ hp0, float* __restrict__ hp1,
                       float* __restrict__ a_s0, float* __restrict__ a_s1,
                       float* __restrict__ a_d0, float* __restrict__ a_d1) {
    int gi = blockIdx.y;
    const float* agg = gi ? agg1 : agg0;
    const float* X = gi ? X1 : X0;
    float* hp = gi ? hp1 : hp0;
    float* a_s = gi ? a_s1 : a_s0;
    float* a_d = gi ? a_d1 : a_d0;
    int n0 = blockIdx.x * 4;
    int o = threadIdx.x; // 128
    __shared__ float xsh[4][FIN];
    __shared__ float h1s[4][HIDD];
    __shared__ float hps[4][HIDD];
    __shared__ float s1[4][2], s2[4][2];
    xsh[o >> 6][o & 63] = X[n0 * FIN + o];
    xsh[(o + 128) >> 6][o & 63] = X[n0 * FIN + o + 128];
    __syncthreads();
    float accs[4];
#pragma unroll
    for (int nn = 0; nn < 4; ++nn) accs[nn] = agg[(size_t)(n0 + nn) * HIDD + o] + cb[o];
#pragma unroll 8
    for (int i = 0; i < FIN; ++i) {
        float w = rw[i * HIDD + o];
#pragma unroll
        for (int nn = 0; nn < 4; ++nn) accs[nn] += xsh[nn][i] * w;
    }
#pragma unroll
    for (int nn = 0; nn < 4; ++nn) h1s[nn][o] = fmaxf(accs[nn], 0.f);
    __syncthreads();
#pragma unroll
    for (int nn = 0; nn < 4; ++nn) accs[nn] = 0.f;
#pragma unroll 8
    for (int k = 0; k < HIDD; ++k) {
        float w = gw[k * HIDD + o];
#pragma unroll
        for (int nn = 0; nn < 4; ++nn) accs[nn] += h1s[nn][k] * w;
    }
#pragma unroll
    for (int nn = 0; nn < 4; ++nn) {
        hps[nn][o] = accs[nn];
        hp[(size_t)(n0 + nn) * HIDD + o] = accs[nn];
    }
#pragma unroll
    for (int nn = 0; nn < 4; ++nn) {
        float v = hps[nn][o];
        float p1 = v * asw[o], p2 = v * adw[o];
#pragma unroll
        for (int off = 32; off; off >>= 1) {
            p1 += __shfl_down(p1, off);
            p2 += __shfl_down(p2, off);
        }
        if ((o & 63) == 0) { s1[nn][o >> 6] = p1; s2[nn][o >> 6] = p2; }
    }
    __syncthreads();
    if (o < 4) {
        a_s[n0 + o] = s1[o][0] + s1[o][1];
        a_d[n0 + o] = s2[o][0] + s2[o][1];
    }
}

// ---------- GAT attention ----------
__global__ void k_evmax(const int* __restrict__ ei0, const int* __restrict__ ei1,
                        const float* __restrict__ a_s0, const float* __restrict__ a_s1,
                        const float* __restrict__ a_d0, const float* __restrict__ a_d1,
                        float* __restrict__ ev0, float* __restrict__ ev1,
                        unsigned* __restrict__ mmax0, unsigned* __restrict__ mmax1) {
    int gi = blockIdx.y;
    const int* src = gi ? ei1 : ei0;
    const int* dst = src + NE;
    const float* a_s = gi ? a_s1 : a_s0;
    const float* a_d = gi ? a_d1 : a_d0;
    float* ev = gi ? ev1 : ev0;
    unsigned* mmax = gi ? mmax1 : mmax0;
    int e = blockIdx.x * blockDim.x + threadIdx.x;
    if (e >= EP) return;
    int si, di;
    if (e < NE) { si = src[e]; di = dst[e]; } else { si = di = e - NE; }
    float x = a_s[si] + a_d[di];
    float v = x > 0.f ? x : 0.2f * x;
    ev[e] = v;
    atomicMax(&mmax[di], enc_f(v));
}

__global__ void k_exden(const int* __restrict__ ei0, const int* __restrict__ ei1,
                        const float* __restrict__ ev0, const float* __restrict__ ev1,
                        const unsigned* __restrict__ mmax0, const unsigned* __restrict__ mmax1,
                        float* __restrict__ ex0, float* __restrict__ ex1,
                        float* __restrict__ denom0, float* __restrict__ denom1) {
    int gi = blockIdx.y;
    const int* dst = (gi ? ei1 : ei0) + NE;
    const float* ev = gi ? ev1 : ev0;
    const unsigned* mmax = gi ? mmax1 : mmax0;
    float* ex = gi ? ex1 : ex0;
    float* denom = gi ? denom1 : denom0;
    int e = blockIdx.x * blockDim.x + threadIdx.x;
    if (e >= EP) return;
    int di = (e < NE) ? dst[e] : e - NE;
    float m = dec_f(mmax[di]);
    float v = expf(ev[e] - m);
    ex[e] = v;
    atomicAdd(&denom[di], v);
}

__global__ void k_gat_scatter(const int* __restrict__ ei0, const int* __restrict__ ei1,
                              const float* __restrict__ ex0, const float* __restrict__ ex1,
                              const float* __restrict__ denom0, const float* __restrict__ denom1,
                              const float* __restrict__ hp0, const float* __restrict__ hp1,
                              float* __restrict__ h2agg0, float* __restrict__ h2agg1) {
    int gi = blockIdx.y;
    const int* src = gi ? ei1 : ei0;
    const int* dst = src + NE;
    const float* ex = gi ? ex1 : ex0;
    const float* denom = gi ? denom1 : denom0;
    const float* hp = gi ? hp1 : hp0;
    float* h2agg = gi ? h2agg1 : h2agg0;
    int e = blockIdx.x * 2 + (threadIdx.x >> 7);
    int o = threadIdx.x & 127;
    int si, di;
    if (e < NE) { si = src[e]; di = dst[e]; } else { si = di = e - NE; }
    float alpha = ex[e] / (denom[di] + 1e-16f);
    atomicAdd(&h2agg[(size_t)di * HIDD + o], alpha * hp[(size_t)si * HIDD + o]);
}

// ---------- mean-pool accumulate ----------
__global__ void k_pool(const float* __restrict__ h2agg0, const float* __restrict__ h2agg1,
                       const float* __restrict__ gb,
                       const int* __restrict__ b0, const int* __restrict__ b1,
                       float* __restrict__ pooled0, float* __restrict__ pooled1,
                       float* __restrict__ cnt0, float* __restrict__ cnt1) {
    int gi = blockIdx.y;
    const float* h2agg = gi ? h2agg1 : h2agg0;
    const int* batch = gi ? b1 : b0;
    float* pooled = gi ? pooled1 : pooled0;
    float* cnt = gi ? cnt1 : cnt0;
    int n = blockIdx.x, o = threadIdx.x;
    int g = batch[n];
    float v = fmaxf(h2agg[(size_t)n * HIDD + o] + gb[o], 0.f);
    atomicAdd(&pooled[g * HIDD + o], v);
    if (o == 0) atomicAdd(&cnt[g], 1.0f);
}

// ---------- fc1 ----------
__global__ void k_fc1(const float* __restrict__ pooled0, const float* __restrict__ pooled1,
                      const float* __restrict__ cnt0, const float* __restrict__ cnt1,
                      const float* __restrict__ w, const float* __restrict__ b,
                      float* __restrict__ z) {
    int gi = blockIdx.y;
    const float* pooled = gi ? pooled1 : pooled0;
    const float* cnt = gi ? cnt1 : cnt0;
    int g = blockIdx.x, j = threadIdx.x; // 64
    float c = fmaxf(cnt[g], 1.0f);
    float acc = b[j];
#pragma unroll 16
    for (int o = 0; o < HIDD; ++o) acc += (pooled[g * HIDD + o] / c) * w[o * OUTD + j];
    z[(size_t)gi * NG * OUTD + g * OUTD + j] = fmaxf(acc, 0.f);
}

// ---------- final ----------
__global__ void k_final(const float* __restrict__ zz,
                        const float* __restrict__ w, const float* __restrict__ b,
                        float* __restrict__ out) {
    int g = threadIdx.x; // 32
    const float* z1 = zz;
    const float* z2 = zz + NG * OUTD;
    float acc = b[0];
#pragma unroll
    for (int j = 0; j < OUTD; ++j) acc += fabsf(z1[g * OUTD + j] - z2[g * OUTD + j]) * w[j];
    out[g] = 1.f / (1.f + expf(-acc));
}

extern "C" void kernel_launch(void* const* d_in, const int* in_sizes, int n_in,
                              void* d_out, int out_size, void* d_ws, size_t ws_size,
                              hipStream_t stream) {
    const float* x0     = (const float*)d_in[0];
    const int*   ei0    = (const int*)d_in[1];
    const float* ea0    = (const float*)d_in[2];
    const int*   b0     = (const int*)d_in[3];
    const float* x1     = (const float*)d_in[4];
    const int*   ei1    = (const int*)d_in[5];
    const float* ea1    = (const float*)d_in[6];
    const int*   b1     = (const int*)d_in[7];
    const float* e_w1 = (const float*)d_in[8];
    const float* e_b1 = (const float*)d_in[9];
    const float* e_w2 = (const float*)d_in[10];
    const float* e_b2 = (const float*)d_in[11];
    const float* e_w3 = (const float*)d_in[12];
    const float* e_b3 = (const float*)d_in[13];
    const float* root_w = (const float*)d_in[14];
    const float* conv1_b = (const float*)d_in[15];
    const float* gat_w = (const float*)d_in[16];
    const float* att_src = (const float*)d_in[17];
    const float* att_dst = (const float*)d_in[18];
    const float* gat_b = (const float*)d_in[19];
    const float* fc1_w = (const float*)d_in[20];
    const float* fc1_b = (const float*)d_in[21];
    const float* fc2_w = (const float*)d_in[22];
    const float* fc2_b = (const float*)d_in[23];

    float* ws = (float*)d_ws;
    size_t off = 0;
    auto alloc = [&](size_t n) { float* p = ws + off; off += n; return p; };
    // zero-region (single memset): agg x2, h2agg x2, mmax x2, denom x2, pooled x2, cnt x2
    float* zero0   = ws;
    float* agg[2]    = {alloc((size_t)NN * HIDD), alloc((size_t)NN * HIDD)};
    float* h2agg[2]  = {alloc((size_t)NN * HIDD), alloc((size_t)NN * HIDD)};
    unsigned* mmax[2] = {(unsigned*)alloc(NN), (unsigned*)alloc(NN)};
    float* denom[2]  = {alloc(NN), alloc(NN)};
    float* pooled[2] = {alloc((size_t)NG * HIDD), alloc((size_t)NG * HIDD)};
    float* cnt[2]    = {alloc(NG), alloc(NG)};
    size_t zero_elems = off;
    // non-zeroed scratch
    float* h[2]   = {alloc((size_t)NE * 64), alloc((size_t)NE * 64)};
    unsigned short* B1g = (unsigned short*)alloc((size_t)4096 * 128 / 2);
    unsigned short* B2g = (unsigned short*)alloc((size_t)4096 * 128 / 2);
    float* Bb[2]  = {alloc((size_t)NN * HIDD), alloc((size_t)NN * HIDD)};
    float* hp[2]  = {alloc((size_t)NN * HIDD), alloc((size_t)NN * HIDD)};
    float* a_s[2] = {alloc(NN), alloc(NN)};
    float* a_d[2] = {alloc(NN), alloc(NN)};
    float* ev[2]  = {alloc(EP), alloc(EP)};
    float* ex[2]  = {alloc(EP), alloc(EP)};
    float* zz     = alloc((size_t)2 * NG * OUTD);

    hipMemsetAsync(zero0, 0, zero_elems * 4, stream);
    k_splitB<<<2048, 256, 0, stream>>>(e_w3, B1g, B2g);
    k_edge_mlp<<<dim3(NE / 8, 2), 128, 0, stream>>>(ea0, ea1, e_w1, e_b1, e_w2, e_b2,
                                                    h[0], h[1]);
    k_bias<<<dim3(NN, 2), HIDD, 0, stream>>>(x0, x1, e_b3, Bb[0], Bb[1]);
    k_nnconv<<<dim3(NE / 128, KSPLIT, 2), 256, 0, stream>>>(
        x0, x1, h[0], h[1], B1g, B2g, Bb[0], Bb[1], ei0, ei1, agg[0], agg[1]);
    k_h1hp<<<dim3(NN / 4, 2), HIDD, 0, stream>>>(
        agg[0], agg[1], x0, x1, root_w, conv1_b, gat_w, att_src, att_dst,
        hp[0], hp[1], a_s[0], a_s[1], a_d[0], a_d[1]);
    k_evmax<<<dim3((EP + 255) / 256, 2), 256, 0, stream>>>(
        ei0, ei1, a_s[0], a_s[1], a_d[0], a_d[1], ev[0], ev[1], mmax[0], mmax[1]);
    k_exden<<<dim3((EP + 255) / 256, 2), 256, 0, stream>>>(
        ei0, ei1, ev[0], ev[1], mmax[0], mmax[1], ex[0], ex[1], denom[0], denom[1]);
    k_gat_scatter<<<dim3(EP / 2, 2), 256, 0, stream>>>(
        ei0, ei1, ex[0], ex[1], denom[0], denom[1], hp[0], hp[1], h2agg[0], h2agg[1]);
    k_pool<<<dim3(NN, 2), HIDD, 0, stream>>>(
        h2agg[0], h2agg[1], gat_b, b0, b1, pooled[0], pooled[1], cnt[0], cnt[1]);
    k_fc1<<<dim3(NG, 2), OUTD, 0, stream>>>(
        pooled[0], pooled[1], cnt[0], cnt[1], fc1_w, fc1_b, zz);
    k_final<<<1, NG, 0, stream>>>(zz, fc2_w, fc2_b, (float*)d_out);
}